// Round 6
// baseline (68.708 us; speedup 1.0000x reference)
//
#include <hip/hip_runtime.h>
#include <math.h>

#define N_HI 192      // IMAGE_RES_OUT * IMAGE_UPSCALE
#define F_HI 128      // FREQ_RES_OUT * FREQ_UPSCALE
#define NOUT 96
#define FOUT 32
#define NB   6        // 5 window buckets + 1 full-eval fallback
#define MAXP 200      // 192 survivors max + slack (one float4 per survivor)
#define NROW 66       // table rows: p-hat = 23.5 + r/4, r in [0,65]
#define P0   23.5f

__device__ __forceinline__ float fast_exp2(float x) {
#if __has_builtin(__builtin_amdgcn_exp2f)
    return __builtin_amdgcn_exp2f(x);
#else
    return exp2f(x);
#endif
}
__device__ __forceinline__ float fast_rcp(float x) {
#if __has_builtin(__builtin_amdgcn_rcpf)
    return __builtin_amdgcn_rcpf(x);
#else
    return 1.0f / x;
#endif
}

__global__ __launch_bounds__(256) void cube_sim_kernel(
    const float* __restrict__ p_inc, const float* __restrict__ p_rot,
    const float* __restrict__ p_lb,  const float* __restrict__ p_vs,
    const float* __restrict__ p_vmax,const float* __restrict__ p_rc,
    const float* __restrict__ p_Rd,  const float* __restrict__ p_hz,
    const float* __restrict__ freqs, float* __restrict__ out)
{
    const int jo   = blockIdx.x;
    const int io   = blockIdx.y;
    const int tid  = threadIdx.x;
    const int col  = tid >> 6;        // wave id = column in the 2x2 hi-res patch
    const int lane = tid & 63;

    __shared__ float  Gtab[NROW * 64];        // shared Gaussian table (16.9 KB)
    __shared__ float4 pairs[4][MAXP];         // per-survivor records (16 B each)
    __shared__ float  acc_s[4][F_HI];         // wave-private channel accumulators

    // ---- uniform scalar setup (fast intrinsics; identical on all threads) ----
    const float FOV    = 500.0f;
    const float C_KMS  = 299792.458f;
    const float F_REST = 230.538f;
    const float LOG2E  = 1.4426950408889634f;

    const float inc    = *p_inc;
    const float rot    = *p_rot;
    const float lb     = *p_lb;
    const float vshift = *p_vs;
    const float vmax   = *p_vmax;
    const float rc     = *p_rc;
    const float Rd     = *p_Rd;
    const float hz     = *p_hz;
    const float f0     = freqs[0];
    const float f_last = freqs[FOUT - 1];

    const float cr = __cosf(rot), sr = __sinf(rot);
    const float ci = __cosf(inc), si = __sinf(inc);

    const float dx     = 2.0f * FOV / (float)(N_HI - 1);
    const float Rmin   = 0.1f * (2.0f * FOV / (float)N_HI);
    const float rc2pm  = rc * rc + Rmin * Rmin;
    const float sig_sq = lb * lb;
    const float nc2    = -(0.5f * fast_rcp(sig_sq)) * LOG2E;  // Gaussian coeff (log2, per km/s^2)
    const float kR     = LOG2E * fast_rcp(Rd);                // intensity radial coeff
    const float kz     = 0.5f * LOG2E * fast_rcp(hz * hz);    // intensity vertical coeff
    const float THR_L  = -16.61f;                             // log2(1e-5) survivor cutoff

    const float fstep = (f_last - f0) * (1.0f / (float)(F_HI - 1));
    const float vlA   = C_KMS * (1.0f - f0 * (1.0f / F_REST)) - vshift;  // vlab(0)
    const float vlB   = -C_KMS * fstep * (1.0f / F_REST);                // vlab step / ch
    const float Dv    = 64.0f * vlB;
    const float c3    = 2.0f * Dv * nc2;                      // full-path delta coeffs
    const float c4    = Dv * Dv * nc2;
    const float invB  = fast_rcp(vlB);
    const float cA    = -vlA * invB;                          // fc = vl*invB + cA
    const float cg    = nc2 * vlB * vlB;                      // Gaussian coeff per ch^2
    const float margin = 5.5f * lb * fabsf(invB);
    const bool  win_ok = (margin <= 23.4f);

    // ---- build shared Gaussian table (all 256 threads) ----
    for (int e = tid; e < NROW * 64; e += 256) {
        const int r = e >> 6, u = e & 63;
        const float d = (float)u - (P0 + 0.25f * (float)r);
        Gtab[e] = fast_exp2(cg * d * d);
    }

    // ---- zero this wave's accumulators (wave-private) ----
    acc_s[col][lane]      = 0.0f;
    acc_s[col][lane + 64] = 0.0f;

    // ---- phase 1: column voxels -> bucket-classified survivor records ----
    const int i = (io << 1) + (col >> 1);
    const int j = (jo << 1) + (col & 1);
    const float x  = -FOV + dx * (float)i;
    const float y  = -FOV + dx * (float)j;
    const float rx = cr * x - sr * y;          // z-independent
    const float y1 = sr * x + cr * y;
    const float ciy1 = ci * y1, siy1 = si * y1;
    const float nsvrx = -si * vmax * rx;
    const float rx2c  = rx * rx + rc2pm;
    const unsigned long long ltm = (1ull << lane) - 1ull;

    float r0_c[3], r1_c[3], r2_c[3];
    int   bk_c[3];
    #pragma unroll
    for (int c = 0; c < 3; ++c) {
        const float z  = -FOV + dx * (float)(c * 64 + lane);
        const float ry = ciy1 - si * z;
        const float rz = siy1 + ci * z;
        const float ry2 = ry * ry;
        const float R  = sqrtf(rx * rx + ry2);
        const float L  = -(R * kR + rz * rz * kz);   // log2 intensity
        const float inv  = __frsqrt_rn(ry2 + rx2c);
        const float vlos = nsvrx * inv;
        const float fc   = __builtin_fmaf(vlos, invB, cA);
        int bk = 7;                                  // 7 = dead
        float r0, r1, r2;
        if (win_ok) {
            int k = (int)rintf((fc - 31.5f) * 0.0625f);
            k = min(max(k, 0), 4);
            if (L >= THR_L) bk = k;
            const float p = fc - 16.0f * (float)k;   // window coord in [23.5, 39.5]
            float t = (p - P0) * 4.0f;               // table phase coord
            t = fminf(fmaxf(t, 0.0f), 64.0f);
            const float rf = floorf(t);
            r0 = __int_as_float(((int)rf) << 6);     // row element-offset r*64
            r1 = t - rf;                             // alpha
            r2 = fast_exp2(L);                       // intensity
        } else {
            if (L >= THR_L) bk = 5;
            r0 = vlos; r1 = L; r2 = 0.0f;
        }
        r0_c[c] = r0; r1_c[c] = r1; r2_c[c] = r2; bk_c[c] = bk;
    }

    // pass A: per-bucket counts
    int cnt[NB];
    #pragma unroll
    for (int k = 0; k < NB; ++k) cnt[k] = 0;
    #pragma unroll
    for (int c = 0; c < 3; ++c)
        #pragma unroll
        for (int k = 0; k < NB; ++k)
            cnt[k] += __popcll(__ballot(bk_c[c] == k));

    // segment bases
    int base[NB];
    {
        int acc = 0;
        #pragma unroll
        for (int k = 0; k < NB; ++k) { base[k] = acc; acc += cnt[k]; }
    }

    // pass B: scatter records into segments
    {
        int run[NB];
        #pragma unroll
        for (int k = 0; k < NB; ++k) run[k] = 0;
        #pragma unroll
        for (int c = 0; c < 3; ++c)
            #pragma unroll
            for (int k = 0; k < NB; ++k) {
                const unsigned long long m = __ballot(bk_c[c] == k);
                if (bk_c[c] == k) {
                    const int pos = base[k] + run[k] + __popcll(m & ltm);
                    pairs[col][pos] = make_float4(r0_c[c], r1_c[c], r2_c[c], 0.0f);
                }
                run[k] += __popcll(m);
            }
    }
    __syncthreads();   // table build complete (pairs are wave-private anyway)

    // ---- phase 2: per-bucket table-lerp accumulation, no exp in the loop ----
    #pragma unroll
    for (int k = 0; k < 5; ++k) {
        const int n = cnt[k];
        if (n > 0) {
            const float4* pp = &pairs[col][base[k]];
            float aw = 0.0f;
            for (int it = 0; it < n; ++it) {
                const float4 q = pp[it];             // wave-uniform broadcast b128
                const int ro = __float_as_int(q.x);
                const float T0 = Gtab[ro + lane];
                const float T1 = Gtab[ro + lane + 64];
                const float G  = __builtin_fmaf(q.y, T1 - T0, T0);
                aw = __builtin_fmaf(G, q.z, aw);
            }
            acc_s[col][16 * k + lane] += aw;         // stride-1, conflict-free
        }
    }
    // bucket 5: full 128-channel exp path (only if margin doesn't fit a window)
    {
        const int n = cnt[5];
        if (n > 0) {
            const float vlab0 = vlA + vlB * (float)lane;
            const float4* pp = &pairs[col][base[5]];
            float a0 = 0.0f, a1 = 0.0f;
            for (int it = 0; it < n; ++it) {
                const float4 q = pp[it];
                const float d0   = vlab0 - q.x;
                const float arg0 = __builtin_fmaf(d0, d0 * nc2, q.y);
                a0 += fast_exp2(arg0);
                a1 += fast_exp2(arg0 + __builtin_fmaf(d0, c3, c4));
            }
            acc_s[col][lane]      += a0;
            acc_s[col][lane + 64] += a1;
        }
    }
    __syncthreads();

    // ---- phase 3: fold 4 cols x 4 freq-subchannels -> 32 outputs ----
    if (tid < FOUT) {
        float s = 0.0f;
        #pragma unroll
        for (int fu = 0; fu < 4; ++fu)
            #pragma unroll
            for (int c2 = 0; c2 < 4; ++c2)
                s += acc_s[c2][4 * tid + fu];
        const float norm16 = (__frsqrt_rn(2.0f * 3.14159265358979f * sig_sq)) * (1.0f / 16.0f);
        out[tid * (NOUT * NOUT) + io * NOUT + jo] = s * norm16;
    }
}

extern "C" void kernel_launch(void* const* d_in, const int* in_sizes, int n_in,
                              void* d_out, int out_size, void* d_ws, size_t ws_size,
                              hipStream_t stream) {
    const float* p_inc  = (const float*)d_in[0];
    const float* p_rot  = (const float*)d_in[1];
    const float* p_lb   = (const float*)d_in[2];
    const float* p_vs   = (const float*)d_in[3];
    const float* p_vmax = (const float*)d_in[4];
    const float* p_rc   = (const float*)d_in[5];
    const float* p_Rd   = (const float*)d_in[6];
    const float* p_hz   = (const float*)d_in[7];
    const float* freqs  = (const float*)d_in[8];
    float* out = (float*)d_out;

    dim3 grid(NOUT, NOUT);
    dim3 block(256);
    cube_sim_kernel<<<grid, block, 0, stream>>>(p_inc, p_rot, p_lb, p_vs,
                                                p_vmax, p_rc, p_Rd, p_hz,
                                                freqs, out);
}

// Round 7
// 38.476 us; speedup vs baseline: 1.7857x; 1.7857x over previous
//
#include <hip/hip_runtime.h>
#include <math.h>

#define N_HI 192      // IMAGE_RES_OUT * IMAGE_UPSCALE
#define F_HI 128      // FREQ_RES_OUT * FREQ_UPSCALE
#define NOUT 96
#define FOUT 32
#define NB   6        // 5 window buckets + 1 full-eval fallback
#define MAXP 212      // 192 survivors + 6*2 pads + even-align slack

__device__ __forceinline__ float fast_exp2(float x) {
#if __has_builtin(__builtin_amdgcn_exp2f)
    return __builtin_amdgcn_exp2f(x);
#else
    return exp2f(x);
#endif
}
__device__ __forceinline__ float fast_rcp(float x) {
#if __has_builtin(__builtin_amdgcn_rcpf)
    return __builtin_amdgcn_rcpf(x);
#else
    return 1.0f / x;
#endif
}

__global__ __launch_bounds__(256) void cube_sim_kernel(
    const float* __restrict__ p_inc, const float* __restrict__ p_rot,
    const float* __restrict__ p_lb,  const float* __restrict__ p_vs,
    const float* __restrict__ p_vmax,const float* __restrict__ p_rc,
    const float* __restrict__ p_Rd,  const float* __restrict__ p_hz,
    const float* __restrict__ freqs, float* __restrict__ out)
{
    const int jo   = blockIdx.x;
    const int io   = blockIdx.y;
    const int tid  = threadIdx.x;
    const int col  = tid >> 6;        // wave id = column in the 2x2 hi-res patch
    const int lane = tid & 63;

    __shared__ alignas(16) float2 pairs[4][MAXP];  // bucket-segmented (u, nL)
    __shared__ float acc_s[4][F_HI];               // wave-private channel accumulators

    // ---- uniform scalar setup (fast intrinsics) ----
    const float FOV    = 500.0f;
    const float C_KMS  = 299792.458f;
    const float F_REST = 230.538f;
    const float LOG2E  = 1.4426950408889634f;

    const float inc    = *p_inc;
    const float rot    = *p_rot;
    const float lb     = *p_lb;
    const float vshift = *p_vs;
    const float vmax   = *p_vmax;
    const float rc     = *p_rc;
    const float Rd     = *p_Rd;
    const float hz     = *p_hz;
    const float f0     = freqs[0];
    const float f_last = freqs[FOUT - 1];

    const float cr = __cosf(rot), sr = __sinf(rot);
    const float ci = __cosf(inc), si = __sinf(inc);

    const float dx     = 2.0f * FOV / (float)(N_HI - 1);
    const float Rmin   = 0.1f * (2.0f * FOV / (float)N_HI);
    const float rc2pm  = rc * rc + Rmin * Rmin;
    const float sig_sq = lb * lb;
    const float pc2    = (0.5f * fast_rcp(sig_sq)) * LOG2E;   // +Gaussian coeff (log2)
    const float kR     = LOG2E * fast_rcp(Rd);                // intensity radial coeff
    const float kz     = 0.5f * LOG2E * fast_rcp(hz * hz);    // intensity vertical coeff
    const float THR_P  = 16.61f;          // -log2(1e-5): survivor cutoff (positive form)

    const float fstep = (f_last - f0) * (1.0f / (float)(F_HI - 1));
    const float vlA   = C_KMS * (1.0f - f0 * (1.0f / F_REST)) - vshift;  // vlab(0)
    const float vlB   = -C_KMS * fstep * (1.0f / F_REST);                // vlab step / ch
    const float Dv    = 64.0f * vlB;
    const float c3    = -2.0f * Dv * pc2;                     // full-path delta coeffs
    const float c4    = -Dv * Dv * pc2;
    const float invB  = fast_rcp(vlB);
    const float cA    = -vlA * invB;                          // fc = vl*invB + cA
    const float cgp   = pc2 * vlB * vlB;                      // +coeff per channel^2
    const float s     = sqrtf(cgp);                           // u-trick scale
    const float s16   = 16.0f * s;
    const float margin = 5.5f * lb * fabsf(invB);
    const bool  win_ok = (margin <= 23.4f);

    // ---- zero this wave's accumulators (wave-private) ----
    acc_s[col][lane]      = 0.0f;
    acc_s[col][lane + 64] = 0.0f;

    // ---- phase 1: column voxels -> bucket-classified survivor records ----
    const int i = (io << 1) + (col >> 1);
    const int j = (jo << 1) + (col & 1);
    const float x  = -FOV + dx * (float)i;
    const float y  = -FOV + dx * (float)j;
    const float rx = cr * x - sr * y;          // z-independent
    const float y1 = sr * x + cr * y;
    const float ciy1 = ci * y1, siy1 = si * y1;
    const float nsvrx = -si * vmax * rx;
    const float rx2   = rx * rx;
    const float rx2c  = rx2 + rc2pm;
    const unsigned long long ltm = (1ull << lane) - 1ull;

    float u_c[3], L_c[3];
    int   bk_c[3];
    #pragma unroll
    for (int c = 0; c < 3; ++c) {
        const float z  = -FOV + dx * (float)(c * 64 + lane);
        const float ry = __builtin_fmaf(-si, z, ciy1);
        const float rz = __builtin_fmaf( ci, z, siy1);
        const float ry2 = ry * ry;
        const float R  = sqrtf(__builtin_fmaf(ry, ry, rx2));
        const float nL = __builtin_fmaf(R, kR, rz * rz * kz);  // -log2 intensity (>=0)
        const float inv  = __frsqrt_rn(ry2 + rx2c);
        const float vlos = nsvrx * inv;
        const float fc   = __builtin_fmaf(vlos, invB, cA);
        int bk = 7;                                  // 7 = dead
        float uu;
        if (win_ok) {
            int k = (int)rintf(__builtin_fmaf(fc, 0.0625f, -1.96875f)); // (fc-31.5)/16
            k = min(max(k, 0), 4);
            if (nL <= THR_P) bk = k;
            uu = __builtin_fmaf(-(float)k, s16, s * fc);   // u = s*(fc - 16k)
        } else {
            if (nL <= THR_P) bk = 5;
            uu = vlos;
        }
        u_c[c] = uu; L_c[c] = nL; bk_c[c] = bk;
    }

    // pass A: ballots once, keep masks; per-bucket counts
    unsigned long long m_ck[3][NB];
    int cnt[NB];
    #pragma unroll
    for (int k = 0; k < NB; ++k) cnt[k] = 0;
    #pragma unroll
    for (int c = 0; c < 3; ++c)
        #pragma unroll
        for (int k = 0; k < NB; ++k) {
            const unsigned long long m = __ballot(bk_c[c] == k);
            m_ck[c][k] = m;
            cnt[k] += __popcll(m);
        }

    // even-aligned segment bases (>=2 pad slots each)
    int base[NB];
    {
        int acc = 0;
        #pragma unroll
        for (int k = 0; k < NB; ++k) { base[k] = acc; acc += (cnt[k] + 3) & ~1; }
    }

    // pass B: scatter records into segments (reuse masks, no new ballots)
    {
        int run[NB];
        #pragma unroll
        for (int k = 0; k < NB; ++k) run[k] = 0;
        #pragma unroll
        for (int c = 0; c < 3; ++c)
            #pragma unroll
            for (int k = 0; k < NB; ++k) {
                const unsigned long long m = m_ck[c][k];
                if ((m >> lane) & 1ull) {
                    const int pos = base[k] + run[k] + __popcll(m & ltm);
                    pairs[col][pos] = make_float2(u_c[c], L_c[c]);
                }
                run[k] += __popcll(m);
            }
    }
    // dead pads (exp2 -> 0) so odd counts / float4 reads are safe
    #pragma unroll
    for (int k = 0; k < NB; ++k)
        if (lane < 2) pairs[col][base[k] + cnt[k] + lane] = make_float2(0.0f, 100000.0f);

    // ---- phase 2: per-bucket windowed eval: 3 VALU + 1 exp per survivor ----
    const float wl = s * (float)lane;
    #pragma unroll
    for (int k = 0; k < 5; ++k) {
        const int nI = (cnt[k] + 1) >> 1;
        if (nI > 0) {
            const float4* pp = reinterpret_cast<const float4*>(&pairs[col][base[k]]);
            float aw = 0.0f;
            for (int it = 0; it < nI; ++it) {
                const float4 q = pp[it];             // wave-uniform broadcast b128
                const float dA = wl - q.x;
                const float dB = wl - q.z;
                const float eA = __builtin_fmaf(dA, dA, q.y);
                const float eB = __builtin_fmaf(dB, dB, q.w);
                aw += fast_exp2(-eA);
                aw += fast_exp2(-eB);
            }
            acc_s[col][16 * k + lane] += aw;         // stride-1, conflict-free
        }
    }
    // bucket 5: full 128-channel path (only if margin doesn't fit a window)
    {
        const int nI = (cnt[5] + 1) >> 1;
        if (nI > 0) {
            const float vlab0 = vlA + vlB * (float)lane;
            const float4* pp = reinterpret_cast<const float4*>(&pairs[col][base[5]]);
            float a0 = 0.0f, a1 = 0.0f;
            for (int it = 0; it < nI; ++it) {
                const float4 q = pp[it];
                {
                    const float d0 = vlab0 - q.x;
                    const float e0 = __builtin_fmaf(d0, d0 * pc2, q.y);
                    a0 += fast_exp2(-e0);
                    a1 += fast_exp2(-(e0 + __builtin_fmaf(d0, c3, c4)));
                }
                {
                    const float d0 = vlab0 - q.z;
                    const float e0 = __builtin_fmaf(d0, d0 * pc2, q.w);
                    a0 += fast_exp2(-e0);
                    a1 += fast_exp2(-(e0 + __builtin_fmaf(d0, c3, c4)));
                }
            }
            acc_s[col][lane]      += a0;
            acc_s[col][lane + 64] += a1;
        }
    }
    __syncthreads();

    // ---- phase 3: fold 4 cols x 4 freq-subchannels -> 32 outputs ----
    if (tid < FOUT) {
        float ssum = 0.0f;
        #pragma unroll
        for (int fu = 0; fu < 4; ++fu)
            #pragma unroll
            for (int c2 = 0; c2 < 4; ++c2)
                ssum += acc_s[c2][4 * tid + fu];
        const float norm16 = __frsqrt_rn(2.0f * 3.14159265358979f * sig_sq) * (1.0f / 16.0f);
        out[tid * (NOUT * NOUT) + io * NOUT + jo] = ssum * norm16;
    }
}

extern "C" void kernel_launch(void* const* d_in, const int* in_sizes, int n_in,
                              void* d_out, int out_size, void* d_ws, size_t ws_size,
                              hipStream_t stream) {
    const float* p_inc  = (const float*)d_in[0];
    const float* p_rot  = (const float*)d_in[1];
    const float* p_lb   = (const float*)d_in[2];
    const float* p_vs   = (const float*)d_in[3];
    const float* p_vmax = (const float*)d_in[4];
    const float* p_rc   = (const float*)d_in[5];
    const float* p_Rd   = (const float*)d_in[6];
    const float* p_hz   = (const float*)d_in[7];
    const float* freqs  = (const float*)d_in[8];
    float* out = (float*)d_out;

    dim3 grid(NOUT, NOUT);
    dim3 block(256);
    cube_sim_kernel<<<grid, block, 0, stream>>>(p_inc, p_rot, p_lb, p_vs,
                                                p_vmax, p_rc, p_Rd, p_hz,
                                                freqs, out);
}

// Round 9
// 33.839 us; speedup vs baseline: 2.0304x; 1.1370x over previous
//
#include <hip/hip_runtime.h>
#include <math.h>

#define N_HI 192      // IMAGE_RES_OUT * IMAGE_UPSCALE
#define F_HI 128      // FREQ_RES_OUT * FREQ_UPSCALE
#define NOUT 96
#define FOUT 32
#define NB   6        // 5 window buckets (pitch 16) + 1 full-eval fallback
#define MAXP 212      // 192 survivors + 6*2 pads + even-align slack

__device__ __forceinline__ float fast_exp2(float x) {
#if __has_builtin(__builtin_amdgcn_exp2f)
    return __builtin_amdgcn_exp2f(x);
#else
    return exp2f(x);
#endif
}
__device__ __forceinline__ float fast_rcp(float x) {
#if __has_builtin(__builtin_amdgcn_rcpf)
    return __builtin_amdgcn_rcpf(x);
#else
    return 1.0f / x;
#endif
}

__global__ __launch_bounds__(256) void cube_sim_kernel(
    const float* __restrict__ p_inc, const float* __restrict__ p_rot,
    const float* __restrict__ p_lb,  const float* __restrict__ p_vs,
    const float* __restrict__ p_vmax,const float* __restrict__ p_rc,
    const float* __restrict__ p_Rd,  const float* __restrict__ p_hz,
    const float* __restrict__ freqs, float* __restrict__ out)
{
    const int jo   = blockIdx.x;
    const int io   = blockIdx.y;
    const int tid  = threadIdx.x;
    const int col  = tid >> 6;        // wave id = column in the 2x2 hi-res patch
    const int lane = tid & 63;

    __shared__ alignas(16) float2 pairs[4][MAXP];  // bucket-segmented (u, nL)
    __shared__ float acc_s[4][F_HI];               // wave-private channel accumulators

    // ---- uniform scalar setup (fast intrinsics) ----
    const float FOV    = 500.0f;
    const float C_KMS  = 299792.458f;
    const float F_REST = 230.538f;
    const float LOG2E  = 1.4426950408889634f;

    const float inc    = *p_inc;
    const float rot    = *p_rot;
    const float lb     = *p_lb;
    const float vshift = *p_vs;
    const float vmax   = *p_vmax;
    const float rc     = *p_rc;
    const float Rd     = *p_Rd;
    const float hz     = *p_hz;
    const float f0     = freqs[0];
    const float f_last = freqs[FOUT - 1];

    const float cr = __cosf(rot), sr = __sinf(rot);
    const float ci = __cosf(inc), si = __sinf(inc);

    const float dx     = 2.0f * FOV / (float)(N_HI - 1);
    const float Rmin   = 0.1f * (2.0f * FOV / (float)N_HI);
    const float rc2pm  = rc * rc + Rmin * Rmin;
    const float sig_sq = lb * lb;
    const float pc2    = (0.5f * fast_rcp(sig_sq)) * LOG2E;   // +Gaussian coeff (log2)
    const float kR     = LOG2E * fast_rcp(Rd);                // intensity radial coeff
    const float kz     = 0.5f * LOG2E * fast_rcp(hz * hz);    // intensity vertical coeff
    const float THR_P  = 13.2877f;        // -log2(1e-4): survivor cutoff (positive form)

    const float fstep = (f_last - f0) * (1.0f / (float)(F_HI - 1));
    const float vlA   = C_KMS * (1.0f - f0 * (1.0f / F_REST)) - vshift;  // vlab(0)
    const float vlB   = -C_KMS * fstep * (1.0f / F_REST);                // vlab step / ch
    const float Dv    = 64.0f * vlB;
    const float c3    = 2.0f * Dv * pc2;                      // full-path delta coeffs
    const float c4    = Dv * Dv * pc2;                        // (sign fixed: e1 = e0 + c3*d0 + c4)
    const float invB  = fast_rcp(vlB);
    const float cA    = -vlA * invB;                          // fc = vl*invB + cA
    const float cgp   = pc2 * vlB * vlB;                      // +coeff per channel^2
    const float s     = sqrtf(cgp);                           // u-trick scale
    const float s16   = 16.0f * s;
    const float margin = 5.5f * lb * fabsf(invB);
    const bool  win_ok = (margin <= 23.4f);

    // ---- zero this wave's accumulators (wave-private) ----
    acc_s[col][lane]      = 0.0f;
    acc_s[col][lane + 64] = 0.0f;

    // ---- phase 1: column voxels -> bucket-classified survivor records ----
    const int i = (io << 1) + (col >> 1);
    const int j = (jo << 1) + (col & 1);
    const float x  = -FOV + dx * (float)i;
    const float y  = -FOV + dx * (float)j;
    const float rx = cr * x - sr * y;          // z-independent
    const float y1 = sr * x + cr * y;
    const float ciy1 = ci * y1, siy1 = si * y1;
    const float nsvrx = -si * vmax * rx;
    const float rx2   = rx * rx;
    const float rx2c  = rx2 + rc2pm;

    float u_c[3], L_c[3];
    int   bk_c[3];
    #pragma unroll
    for (int c = 0; c < 3; ++c) {
        const float z  = -FOV + dx * (float)(c * 64 + lane);
        const float ry = __builtin_fmaf(-si, z, ciy1);
        const float rz = __builtin_fmaf( ci, z, siy1);
        const float ry2 = ry * ry;
        const float R  = sqrtf(__builtin_fmaf(ry, ry, rx2));
        const float nL = __builtin_fmaf(R, kR, rz * rz * kz);  // -log2 intensity (>=0)
        const float inv  = __frsqrt_rn(ry2 + rx2c);
        const float vlos = nsvrx * inv;
        const float fc   = __builtin_fmaf(vlos, invB, cA);
        int bk = 7;                                  // 7 = dead
        float uu;
        if (win_ok) {
            int k = (int)rintf(__builtin_fmaf(fc, 0.0625f, -1.96875f)); // (fc-31.5)/16
            k = min(max(k, 0), 4);
            if (nL <= THR_P) bk = k;
            uu = __builtin_fmaf(-(float)k, s16, s * fc);   // u = s*(fc - 16k)
        } else {
            if (nL <= THR_P) bk = 5;
            uu = vlos;
        }
        u_c[c] = uu; L_c[c] = nL; bk_c[c] = bk;
    }

    // pass A: ballots once, keep masks; per-bucket counts
    unsigned long long m_ck[3][NB];
    int cnt[NB];
    #pragma unroll
    for (int k = 0; k < NB; ++k) cnt[k] = 0;
    #pragma unroll
    for (int c = 0; c < 3; ++c)
        #pragma unroll
        for (int k = 0; k < NB; ++k) {
            const unsigned long long m = __ballot(bk_c[c] == k);
            m_ck[c][k] = m;
            cnt[k] += (int)__popcll(m);
        }

    // even-aligned segment bases (>=2 pad slots each)
    int base[NB];
    {
        int acc = 0;
        #pragma unroll
        for (int k = 0; k < NB; ++k) { base[k] = acc; acc += (cnt[k] + 3) & ~1; }
    }

    // pass B: scatter records (rank via mbcnt)
    {
        int run[NB];
        #pragma unroll
        for (int k = 0; k < NB; ++k) run[k] = 0;
        #pragma unroll
        for (int c = 0; c < 3; ++c)
            #pragma unroll
            for (int k = 0; k < NB; ++k) {
                const unsigned long long m = m_ck[c][k];
                if (bk_c[c] == k) {
                    const int rank = (int)__builtin_amdgcn_mbcnt_hi(
                        (unsigned)(m >> 32),
                        __builtin_amdgcn_mbcnt_lo((unsigned)m, 0u));
                    pairs[col][base[k] + run[k] + rank] = make_float2(u_c[c], L_c[c]);
                }
                run[k] += (int)__popcll(m);
            }
    }
    // dead pads (exp2 -> 0) so odd counts / float4 reads are safe
    #pragma unroll
    for (int k = 0; k < NB; ++k)
        if (lane < 2) pairs[col][base[k] + cnt[k] + lane] = make_float2(0.0f, 100000.0f);

    // ---- phase 2: per-bucket windowed eval: sub+fma+exp+add per survivor ----
    const float wl = s * (float)lane;
    #pragma unroll
    for (int k = 0; k < 5; ++k) {
        const int nI = (cnt[k] + 1) >> 1;
        if (nI > 0) {
            const float4* pp = reinterpret_cast<const float4*>(&pairs[col][base[k]]);
            float aw = 0.0f;
            for (int it = 0; it < nI; ++it) {
                const float4 q = pp[it];             // wave-uniform broadcast b128
                const float dA = wl - q.x;
                const float dB = wl - q.z;
                aw += fast_exp2(-__builtin_fmaf(dA, dA, q.y));
                aw += fast_exp2(-__builtin_fmaf(dB, dB, q.w));
            }
            acc_s[col][16 * k + lane] += aw;         // stride-1, conflict-free
        }
    }
    // bucket 5: full 128-channel path (only if margin doesn't fit a window)
    {
        const int nI = (cnt[5] + 1) >> 1;
        if (nI > 0) {
            const float vlab0 = vlA + vlB * (float)lane;
            const float4* pp = reinterpret_cast<const float4*>(&pairs[col][base[5]]);
            float a0 = 0.0f, a1 = 0.0f;
            for (int it = 0; it < nI; ++it) {
                const float4 q = pp[it];
                {
                    const float d0 = vlab0 - q.x;
                    const float e0 = __builtin_fmaf(d0, d0 * pc2, q.y);
                    a0 += fast_exp2(-e0);
                    a1 += fast_exp2(-(e0 + __builtin_fmaf(d0, c3, c4)));
                }
                {
                    const float d0 = vlab0 - q.z;
                    const float e0 = __builtin_fmaf(d0, d0 * pc2, q.w);
                    a0 += fast_exp2(-e0);
                    a1 += fast_exp2(-(e0 + __builtin_fmaf(d0, c3, c4)));
                }
            }
            acc_s[col][lane]      += a0;
            acc_s[col][lane + 64] += a1;
        }
    }
    __syncthreads();

    // ---- phase 3: fold 4 cols x 4 freq-subchannels -> 32 outputs ----
    if (tid < FOUT) {
        float ssum = 0.0f;
        #pragma unroll
        for (int fu = 0; fu < 4; ++fu)
            #pragma unroll
            for (int c2 = 0; c2 < 4; ++c2)
                ssum += acc_s[c2][4 * tid + fu];
        const float norm16 = __frsqrt_rn(2.0f * 3.14159265358979f * sig_sq) * (1.0f / 16.0f);
        out[tid * (NOUT * NOUT) + io * NOUT + jo] = ssum * norm16;
    }
}

extern "C" void kernel_launch(void* const* d_in, const int* in_sizes, int n_in,
                              void* d_out, int out_size, void* d_ws, size_t ws_size,
                              hipStream_t stream) {
    const float* p_inc  = (const float*)d_in[0];
    const float* p_rot  = (const float*)d_in[1];
    const float* p_lb   = (const float*)d_in[2];
    const float* p_vs   = (const float*)d_in[3];
    const float* p_vmax = (const float*)d_in[4];
    const float* p_rc   = (const float*)d_in[5];
    const float* p_Rd   = (const float*)d_in[6];
    const float* p_hz   = (const float*)d_in[7];
    const float* freqs  = (const float*)d_in[8];
    float* out = (float*)d_out;

    dim3 grid(NOUT, NOUT);
    dim3 block(256);
    cube_sim_kernel<<<grid, block, 0, stream>>>(p_inc, p_rot, p_lb, p_vs,
                                                p_vmax, p_rc, p_Rd, p_hz,
                                                freqs, out);
}